// Round 5
// baseline (149.696 us; speedup 1.0000x reference)
//
#include <hip/hip_runtime.h>
#include <math.h>

#define TWO_PI_F 6.28318530717958647692f
#define PI_F     3.14159265358979323846f

__device__ __forceinline__ float warp_sum(float s) {
    #pragma unroll
    for (int off = 32; off; off >>= 1) s += __shfl_xor(s, off, 64);
    return s;
}
__device__ __forceinline__ float warp_max(float m) {
    #pragma unroll
    for (int off = 32; off; off >>= 1) m = fmaxf(m, __shfl_xor(m, off, 64));
    return m;
}

__device__ __forceinline__ float edge_wrap(float a, float b) {
    float d = fabsf(a - b);
    d = fmodf(d, TWO_PI_F);
    return (d > PI_F) ? (TWO_PI_F - d) : d;
}

// -log_softmax(row)[t], wave-uniform return value.
__device__ __forceinline__ float ce_row(const float* __restrict__ rowp,
                                        int C, int lane, int t) {
    const float4* row4 = (const float4*)rowp;
    const int nf4 = C >> 2;
    const float tv = rowp[t];                 // same addr all lanes -> broadcast
    float m, s;
    if (nf4 <= 256) {
        // whole row in 4 named float4 regs/lane (no arrays -> no LDS demotion)
        const float4 NEG = make_float4(-INFINITY, -INFINITY, -INFINITY, -INFINITY);
        const int j0 = lane, j1 = lane + 64, j2 = lane + 128, j3 = lane + 192;
        float4 v0 = (j0 < nf4) ? row4[j0] : NEG;
        float4 v1 = (j1 < nf4) ? row4[j1] : NEG;
        float4 v2 = (j2 < nf4) ? row4[j2] : NEG;
        float4 v3 = (j3 < nf4) ? row4[j3] : NEG;
        const int remBase = nf4 << 2;
        float tail = (remBase + lane < C) ? rowp[remBase + lane] : -INFINITY;

        m = tail;
        m = fmaxf(m, fmaxf(fmaxf(v0.x, v0.y), fmaxf(v0.z, v0.w)));
        m = fmaxf(m, fmaxf(fmaxf(v1.x, v1.y), fmaxf(v1.z, v1.w)));
        m = fmaxf(m, fmaxf(fmaxf(v2.x, v2.y), fmaxf(v2.z, v2.w)));
        m = fmaxf(m, fmaxf(fmaxf(v3.x, v3.y), fmaxf(v3.z, v3.w)));
        m = warp_max(m);

        s  = __expf(v0.x - m) + __expf(v0.y - m) + __expf(v0.z - m) + __expf(v0.w - m);
        s += __expf(v1.x - m) + __expf(v1.y - m) + __expf(v1.z - m) + __expf(v1.w - m);
        s += __expf(v2.x - m) + __expf(v2.y - m) + __expf(v2.z - m) + __expf(v2.w - m);
        s += __expf(v3.x - m) + __expf(v3.y - m) + __expf(v3.z - m) + __expf(v3.w - m);
        s += __expf(tail - m);
        s = warp_sum(s);
    } else {
        // generic fallback: two passes, re-read global (L2-hot)
        m = -INFINITY;
        for (int j = lane; j < nf4; j += 64) {
            float4 x = row4[j];
            m = fmaxf(m, fmaxf(fmaxf(x.x, x.y), fmaxf(x.z, x.w)));
        }
        const int remBase = nf4 << 2;
        if (remBase + lane < C) m = fmaxf(m, rowp[remBase + lane]);
        m = warp_max(m);
        s = 0.0f;
        for (int j = lane; j < nf4; j += 64) {
            float4 x = row4[j];
            s += __expf(x.x - m) + __expf(x.y - m) + __expf(x.z - m) + __expf(x.w - m);
        }
        if (remBase + lane < C) s += __expf(rowp[remBase + lane] - m);
        s = warp_sum(s);
    }
    return m + __logf(s) - tv;
}

// Stage 1: fused CE + resonance; one plain partial store per block.
//   blocks [0, res_blocks)          : 4 edges/thread, int4 index loads, 8
//                                     outstanding gathers/thread (MLP)
//   blocks [res_blocks, +ce_blocks) : 2 CE rows per wave
__global__ __launch_bounds__(256) void fused_kernel(
    const float* __restrict__ outputs,
    const int*   __restrict__ targets,
    const float* __restrict__ phase,
    const int*   __restrict__ esrc,
    const int*   __restrict__ edst,
    int B, int C, int N, int E,
    int res_blocks,
    float invB, float scaleE,
    float* __restrict__ ws)
{
    __shared__ float part[4];
    const int lane = threadIdx.x & 63;
    const int wave = threadIdx.x >> 6;

    float wsum = 0.0f;

    if ((int)blockIdx.x < res_blocks) {
        const int base = (blockIdx.x * 256 + threadIdx.x) * 4;
        float d = 0.0f;
        if (base + 3 < E) {
            const int4 s4 = *(const int4*)(esrc + base);
            const int4 t4 = *(const int4*)(edst + base);
            const float a0 = phase[(size_t)s4.x * (size_t)N + (size_t)t4.x];
            const float b0 = phase[(size_t)t4.x * (size_t)N + (size_t)s4.x];
            const float a1 = phase[(size_t)s4.y * (size_t)N + (size_t)t4.y];
            const float b1 = phase[(size_t)t4.y * (size_t)N + (size_t)s4.y];
            const float a2 = phase[(size_t)s4.z * (size_t)N + (size_t)t4.z];
            const float b2 = phase[(size_t)t4.z * (size_t)N + (size_t)s4.z];
            const float a3 = phase[(size_t)s4.w * (size_t)N + (size_t)t4.w];
            const float b3 = phase[(size_t)t4.w * (size_t)N + (size_t)s4.w];
            d = edge_wrap(a0, b0) + edge_wrap(a1, b1)
              + edge_wrap(a2, b2) + edge_wrap(a3, b3);
        } else {
            for (int i = base; i < E; i++) {
                const int s = esrc[i], t = edst[i];
                d += edge_wrap(phase[(size_t)s * (size_t)N + (size_t)t],
                               phase[(size_t)t * (size_t)N + (size_t)s]);
            }
        }
        d = warp_sum(d);
        if (lane == 0) wsum = d * scaleE;
    } else {
        const int row0 = ((int)blockIdx.x - res_blocks) * 8 + wave * 2;
        if (row0 < B) {
            const int t0 = targets[row0];
            const float c0 = ce_row(outputs + (size_t)row0 * (size_t)C, C, lane, t0);
            if (lane == 0) wsum += c0 * invB;
        }
        if (row0 + 1 < B) {
            const int t1 = targets[row0 + 1];
            const float c1 = ce_row(outputs + (size_t)(row0 + 1) * (size_t)C, C, lane, t1);
            if (lane == 0) wsum += c1 * invB;
        }
    }

    if (lane == 0) part[wave] = wsum;
    __syncthreads();
    if (threadIdx.x == 0)
        ws[blockIdx.x] = part[0] + part[1] + part[2] + part[3];
}

// Stage 2: one block reduces all partials.
__global__ __launch_bounds__(256) void reduce_kernel(
    const float* __restrict__ ws, int P, float* __restrict__ out)
{
    float s = 0.0f;
    for (int i = threadIdx.x; i < P; i += 256)
        s += ws[i];
    s = warp_sum(s);
    __shared__ float part[4];
    if ((threadIdx.x & 63) == 0) part[threadIdx.x >> 6] = s;
    __syncthreads();
    if (threadIdx.x == 0)
        out[0] = part[0] + part[1] + part[2] + part[3];
}

extern "C" void kernel_launch(void* const* d_in, const int* in_sizes, int n_in,
                              void* d_out, int out_size, void* d_ws, size_t ws_size,
                              hipStream_t stream) {
    const float* outputs = (const float*)d_in[0];
    const int*   targets = (const int*)d_in[1];
    const float* phase   = (const float*)d_in[2];
    const int*   esrc    = (const int*)d_in[3];
    const int*   edst    = (const int*)d_in[4];

    const int B = in_sizes[1];
    const int C = in_sizes[0] / B;
    const int E = in_sizes[3];
    int N = 1;
    while ((long long)N * (long long)N < (long long)in_sizes[2]) N++;

    const int res_blocks = (E + 1023) / 1024;        // 128 (4 edges/thread)
    const int ce_blocks  = (B + 7) / 8;              // 2048 (2 rows/wave)
    const int grid = res_blocks + ce_blocks;         // 2176 partials

    float* ws = (float*)d_ws;

    fused_kernel<<<grid, 256, 0, stream>>>(outputs, targets, phase, esrc, edst,
                                           B, C, N, E, res_blocks,
                                           1.0f / (float)B, 0.1f / (float)E,
                                           ws);
    reduce_kernel<<<1, 256, 0, stream>>>(ws, grid, (float*)d_out);
}